// Round 4
// baseline (105.858 us; speedup 1.0000x reference)
//
#include <hip/hip_runtime.h>
#include <hip/hip_bf16.h>

#define NS 64
#define DIM 128
#define BATCH_N 16384

typedef float f32x4 __attribute__((ext_vector_type(4)));
typedef _Float16 f16x8 __attribute__((ext_vector_type(8)));
typedef unsigned int u32;
typedef unsigned long long u64;

// fp32 -> fp16 (RNE via hardware cvt)
__device__ __forceinline__ unsigned short f2h(float f) {
    _Float16 h = (_Float16)f;
    return __builtin_bit_cast(unsigned short, h);
}

// ---------------------------------------------------------------------------
// prep 1: build fp16 MFMA A-operand fragments in d_ws.
// Layout: frag[s][t][kk][mm8][lane][j] ; t=0 -> A0, t=1 -> D = A1-A0
// value = M[kk*32 + (lane>>4)*8 + j][mm8*16 + (lane&15)]
// ---------------------------------------------------------------------------
__global__ void prep_frags(const float* __restrict__ data,
                           unsigned short* __restrict__ afrag) {
    int idx = blockIdx.x * blockDim.x + threadIdx.x;
    if (idx >= 64 * 2 * 4 * 8 * 64) return;
    int l  = idx & 63;
    int mm = (idx >> 6) & 7;
    int kk = (idx >> 9) & 3;
    int t  = (idx >> 11) & 1;
    int s  = idx >> 12;
    int m = mm * 16 + (l & 15);
    int kbase = kk * 32 + (l >> 4) * 8;
    const float* a0 = data + ((size_t)s * 2 + 0) * DIM * DIM;
    const float* a1 = a0 + DIM * DIM;
    unsigned short outv[8];
#pragma unroll
    for (int j = 0; j < 8; ++j) {
        int k = kbase + j;
        float v0 = a0[k * DIM + m];
        float vv = (t == 0) ? v0 : (a1[k * DIM + m] - v0);
        outv[j] = f2h(vv);
    }
    *reinterpret_cast<uint4*>(afrag + (size_t)idx * 8) =
        *reinterpret_cast<uint4*>(outv);
}

// ---------------------------------------------------------------------------
// prep 2: pack occupation bits, one u64 per batch row
// ---------------------------------------------------------------------------
__global__ void prep_bits(const int* __restrict__ onstate,
                          const int* __restrict__ image2,
                          u64* __restrict__ bits) {
    int r = blockIdx.x * blockDim.x + threadIdx.x;
    if (r >= BATCH_N) return;
    const int* row = onstate + (size_t)r * NS;
    u64 b = 0;
#pragma unroll 8
    for (int t = 0; t < NS; ++t) {
        b |= ((u64)(row[image2[t]] & 1)) << t;
    }
    bits[r] = b;
}

// ---------------------------------------------------------------------------
// main: 256 blocks x 512 threads (8 waves, 2/SIMD); block owns 64 batch rows.
// Wave (mt = wid>>1, rh = wid&1): m-tile of 32 dims (mt), row-half of 32 (rh).
// Halves LDS v-read duplication (4x vs 8x) at the cost of 2x A-reads from L2;
// adjacent waves (2w, 2w+1) share the same A-fragments -> L1 catches the dup.
// A-fragments fully double-buffered in registers across sites.
// ---------------------------------------------------------------------------
__global__ __launch_bounds__(512, 2)
void mps_main(const unsigned short* __restrict__ afrag,
              const u64* __restrict__ occbits,
              const float* __restrict__ left,
              const float* __restrict__ right,
              float* __restrict__ out) {
    __shared__ unsigned short vlds[2][64 * DIM];   // 2 x 16 KB, fp16 v, swizzled
    __shared__ float red[64][17];                  // final reduction scratch

    const int tid  = threadIdx.x;
    const int wid  = tid >> 6;
    const int lane = tid & 63;
    const int li   = lane & 15;
    const int g    = lane >> 4;
    const int mt   = wid >> 1;          // 0..3: which 32-wide m-tile
    const int rh   = wid & 1;           // 0..1: which 32-row half
    const int rbase = blockIdx.x * 64;

    // occupation bits for this lane's 2 rows
    u64 bits[2];
#pragma unroll
    for (int rr = 0; rr < 2; ++rr)
        bits[rr] = occbits[rbase + rh * 32 + rr * 16 + li];

    // hoisted LDS byte offsets (site-invariant)
    u32 rdoff[2][4];
#pragma unroll
    for (int rr = 0; rr < 2; ++rr)
#pragma unroll
        for (int kk = 0; kk < 4; ++kk) {
            int r = rh * 32 + rr * 16 + li;
            rdoff[rr][kk] =
                (u32)(r * 256 + kk * 64 + g * 16) ^ ((u32)(r & 7) << 4);
        }
    u32 wroff[2][2];
#pragma unroll
    for (int mm = 0; mm < 2; ++mm)
#pragma unroll
        for (int rr = 0; rr < 2; ++rr) {
            int r = rh * 32 + rr * 16 + li;
            int mcol = (mt * 2 + mm) * 16 + g * 4;
            wroff[mm][rr] =
                (u32)(r * 256 + mcol * 2) ^ ((u32)(r & 7) << 4);
        }

    // init v buffer 0 with fp16(left), swizzled
    for (int c = tid; c < 64 * 16; c += 512) {
        int r  = c >> 4;
        int kc = c & 15;
        unsigned short tmp[8];
#pragma unroll
        for (int j = 0; j < 8; ++j) tmp[j] = f2h(left[kc * 8 + j]);
        u32 byte = (u32)(r * 256 + kc * 16) ^ ((u32)(r & 7) << 4);
        *reinterpret_cast<uint4*>(reinterpret_cast<char*>(&vlds[0][0]) + byte) =
            *reinterpret_cast<uint4*>(tmp);
    }
    __syncthreads();

    const f16x8 zf = {0, 0, 0, 0, 0, 0, 0, 0};

    f16x8 fa[2][2][4], fd[2][2][4];   // [buf][mm][kk] A-frag double buffer

#define ISSUE(BUF, S_)                                                        \
    {                                                                         \
        const unsigned short* sb_ = afrag + (size_t)(S_) * 32768;             \
        _Pragma("unroll")                                                     \
        for (int mm = 0; mm < 2; ++mm)                                        \
            _Pragma("unroll")                                                 \
            for (int kk = 0; kk < 4; ++kk) {                                  \
                fa[BUF][mm][kk] = *reinterpret_cast<const f16x8*>(            \
                    sb_ + ((size_t)((0 * 4 + kk) * 8 + mt * 2 + mm) * 512) +  \
                    lane * 8);                                                \
                fd[BUF][mm][kk] = *reinterpret_cast<const f16x8*>(            \
                    sb_ + ((size_t)((1 * 4 + kk) * 8 + mt * 2 + mm) * 512) +  \
                    lane * 8);                                                \
            }                                                                 \
    }

#define COMPUTE(S_, BUF)                                                      \
    {                                                                         \
        const int s_ = (S_);                                                  \
        const char* vb = reinterpret_cast<const char*>(&vlds[s_ & 1][0]);     \
        char*       wb = reinterpret_cast<char*>(&vlds[(s_ + 1) & 1][0]);     \
        f32x4 acc[2][2];                                                      \
        _Pragma("unroll")                                                     \
        for (int mm = 0; mm < 2; ++mm)                                        \
            _Pragma("unroll")                                                 \
            for (int rr = 0; rr < 2; ++rr)                                    \
                acc[mm][rr] = (f32x4){0.f, 0.f, 0.f, 0.f};                    \
        f16x8 bfr[2][4];                                                      \
        _Pragma("unroll")                                                     \
        for (int kk = 0; kk < 4; ++kk)                                        \
            _Pragma("unroll")                                                 \
            for (int rr = 0; rr < 2; ++rr)                                    \
                bfr[rr][kk] =                                                 \
                    *reinterpret_cast<const f16x8*>(vb + rdoff[rr][kk]);      \
        _Pragma("unroll")                                                     \
        for (int kk = 0; kk < 4; ++kk) {                                      \
            _Pragma("unroll")                                                 \
            for (int rr = 0; rr < 2; ++rr) {                                  \
                bool mk = (bits[rr] >> s_) & 1;                               \
                f16x8 mb = mk ? bfr[rr][kk] : zf;                             \
                _Pragma("unroll")                                             \
                for (int mm = 0; mm < 2; ++mm) {                              \
                    acc[mm][rr] = __builtin_amdgcn_mfma_f32_16x16x32_f16(     \
                        fa[BUF][mm][kk], bfr[rr][kk], acc[mm][rr], 0, 0, 0);  \
                    acc[mm][rr] = __builtin_amdgcn_mfma_f32_16x16x32_f16(     \
                        fd[BUF][mm][kk], mb, acc[mm][rr], 0, 0, 0);           \
                }                                                             \
            }                                                                 \
        }                                                                     \
        if (s_ < NS - 1) {                                                    \
            _Pragma("unroll")                                                 \
            for (int mm = 0; mm < 2; ++mm)                                    \
                _Pragma("unroll")                                             \
                for (int rr = 0; rr < 2; ++rr) {                              \
                    u32 lo = ((u32)f2h(acc[mm][rr][1]) << 16) |               \
                             f2h(acc[mm][rr][0]);                             \
                    u32 hi = ((u32)f2h(acc[mm][rr][3]) << 16) |               \
                             f2h(acc[mm][rr][2]);                             \
                    uint2 w = {lo, hi};                                       \
                    *reinterpret_cast<uint2*>(wb + wroff[mm][rr]) = w;        \
                }                                                             \
            __syncthreads();                                                  \
        } else {                                                              \
            _Pragma("unroll")                                                 \
            for (int rr = 0; rr < 2; ++rr) {                                  \
                float p = 0.f;                                                \
                _Pragma("unroll")                                             \
                for (int mm = 0; mm < 2; ++mm) {                              \
                    int mcol = (mt * 2 + mm) * 16 + g * 4;                    \
                    const float4 rv =                                         \
                        *reinterpret_cast<const float4*>(right + mcol);       \
                    p += acc[mm][rr][0] * rv.x + acc[mm][rr][1] * rv.y +      \
                         acc[mm][rr][2] * rv.z + acc[mm][rr][3] * rv.w;       \
                }                                                             \
                red[rh * 32 + rr * 16 + li][mt * 4 + g] = p;                  \
            }                                                                 \
            __syncthreads();                                                  \
            if (tid < 64) {                                                   \
                float ssum = 0.f;                                             \
                _Pragma("unroll")                                             \
                for (int i = 0; i < 16; ++i) ssum += red[tid][i];             \
                out[rbase + tid] = ssum;                                      \
            }                                                                 \
        }                                                                     \
    }

    ISSUE(0, 0);
    for (int sp = 0; sp < NS; sp += 2) {
        ISSUE(1, sp + 1);                            // prefetch odd site
        COMPUTE(sp, 0);
        if (sp + 2 < NS) ISSUE(0, sp + 2);           // prefetch next even site
        COMPUTE(sp + 1, 1);
    }

#undef ISSUE
#undef COMPUTE
}

// ---------------------------------------------------------------------------
extern "C" void kernel_launch(void* const* d_in, const int* in_sizes, int n_in,
                              void* d_out, int out_size, void* d_ws, size_t ws_size,
                              hipStream_t stream) {
    const int*   onstate = (const int*)d_in[0];
    const float* data    = (const float*)d_in[1];
    const float* left    = (const float*)d_in[2];
    const float* right   = (const float*)d_in[3];
    const int*   image2  = (const int*)d_in[4];
    float* out = (float*)d_out;

    unsigned short* afrag = (unsigned short*)d_ws;                       // 4 MB
    u64* bits = (u64*)((char*)d_ws + (size_t)2097152 * sizeof(unsigned short));

    prep_frags<<<1024, 256, 0, stream>>>(data, afrag);   // 262144 threads
    prep_bits<<<64, 256, 0, stream>>>(onstate, image2, bits);
    mps_main<<<256, 512, 0, stream>>>(afrag, bits, left, right, out);
}